// Round 4
// baseline (401.953 us; speedup 1.0000x reference)
//
#include <hip/hip_runtime.h>

// Problem constants (match reference)
#define NROWS   262144
#define DIM     256
#define CLUSTER 512
#define NPAIR   (CLUSTER * (CLUSTER - 1) / 2)   // 130816
#define G       16                               // cluster groups (32 clusters each)
#define CPG     32                               // clusters per group
#define R       64                               // row chunks
#define CHUNK   (NROWS / R)                      // 4096 rows per chunk
#define PAIR_BLOCKS 2044                         // 2044 * 4 waves * 16 pairs = 130816 exactly

// ---------------- K1: local counting-sort + register-accumulated sums -------
// Block (g, r): builds per-cluster contiguous lists of local row indices
// (count -> scan -> place, capacity CHUNK so overflow is impossible), then
// wave w walks clusters {w, w+4, ..., w+28} segment-by-segment with the
// 4-float accumulator in VGPRs (no LDS RMW chain -> global loads pipeline),
// writing each finished cluster-partial straight to global.
// Matrix rows are read exactly once device-wide.
__global__ __launch_bounds__(256) void k_gather(const float* __restrict__ matrix,
                                                const int* __restrict__ label,
                                                float* __restrict__ partial,    // [CLUSTER][R][DIM]
                                                int* __restrict__ countpart) {  // [R][CLUSTER]
    int g = blockIdx.x & (G - 1);
    int r = blockIdx.x >> 4;           // 0..R-1
    int t = threadIdx.x;
    int w = t >> 6, lane = t & 63;
    int base = r * CHUNK;

    __shared__ unsigned short list[CHUNK];   // 8 KB, segmented by cluster
    __shared__ int cnt[CPG];
    __shared__ int off[CPG + 1];
    __shared__ int cur[CPG];

    if (t < CPG) cnt[t] = 0;
    __syncthreads();

    // pass 1: count rows per local cluster
    for (int i = t; i < CHUNK; i += 256) {
        int lab = label[base + i];
        if ((lab >> 5) == g) atomicAdd(&cnt[lab & (CPG - 1)], 1);
    }
    __syncthreads();

    // tiny exclusive scan (serial, 32 elements)
    if (t == 0) {
        int s = 0;
        #pragma unroll
        for (int c = 0; c < CPG; ++c) { off[c] = s; cur[c] = s; s += cnt[c]; }
        off[CPG] = s;
    }
    __syncthreads();

    // pass 2: place local row indices into cluster segments (labels L2-hot)
    for (int i = t; i < CHUNK; i += 256) {
        int lab = label[base + i];
        if ((lab >> 5) == g) {
            int p = atomicAdd(&cur[lab & (CPG - 1)], 1);
            list[p] = (unsigned short)i;
        }
    }
    __syncthreads();

    // accumulate: wave w owns clusters cl = 4q + w, acc lives in VGPRs
    #pragma unroll
    for (int q = 0; q < 8; ++q) {
        int cl = q * 4 + w;
        int s0 = off[cl], s1 = off[cl + 1];
        float ax = 0.f, ay = 0.f, az = 0.f, aw = 0.f;
        #pragma unroll 4
        for (int k = s0; k < s1; ++k) {
            int li = list[k];   // wave-uniform LDS broadcast
            const float4* row = (const float4*)(matrix + (size_t)(base + li) * DIM);
            float4 v = row[lane];
            ax += v.x; ay += v.y; az += v.z; aw += v.w;
        }
        int c = g * CPG + cl;
        ((float4*)(partial + ((size_t)c * R + r) * DIM))[lane] =
            make_float4(ax, ay, az, aw);
    }
    if (t < CPG) countpart[r * CLUSTER + g * CPG + t] = cnt[t];
}

// ---------------- K2: reduce chunk partials -> centers ----------------------
__global__ __launch_bounds__(256) void k_center(const float* __restrict__ partial,
                                                const int* __restrict__ countpart,
                                                float* __restrict__ centers) {
    int c = blockIdx.x, d = threadIdx.x;
    __shared__ float invc;
    if (d == 0) {
        int s = 0;
        for (int r = 0; r < R; ++r) s += countpart[r * CLUSTER + c];
        invc = 1.0f / (float)max(s, 1);
    }
    float acc = 0.f;
    const float* p = partial + (size_t)c * R * DIM + d;   // contiguous 64 KB per block
    #pragma unroll 8
    for (int r = 0; r < R; ++r) acc += p[r * DIM];
    __syncthreads();
    centers[c * DIM + d] = acc * invc;
}

// ---------------- K3: pairwise distances, 16 pairs per wave -----------------
__device__ __forceinline__ long long tri_off(long long i) {
    return i * (2 * CLUSTER - i - 1) / 2;
}

__global__ __launch_bounds__(256) void k_pairs(const float* __restrict__ centers,
                                               float* __restrict__ partials) {
    int wave = threadIdx.x >> 6;
    int lane = threadIdx.x & 63;
    long long base = ((long long)blockIdx.x * 4 + wave) * 16;  // first pair, < NPAIR

    // invert triangular index once per wave
    double sq = sqrt((double)((2LL * CLUSTER - 1) * (2LL * CLUSTER - 1) - 8 * base));
    int i = (int)(((2 * CLUSTER - 1) - sq) * 0.5);
    if (i < 0) i = 0;
    while (tri_off(i + 1) <= base) ++i;
    while (tri_off(i) > base) --i;
    int j = (int)(base - tri_off(i)) + i + 1;

    float wsum = 0.f;
    #pragma unroll 4
    for (int q = 0; q < 16; ++q) {
        const float4* ci = (const float4*)(centers + (size_t)i * DIM);
        const float4* cj = (const float4*)(centers + (size_t)j * DIM);
        float4 a = ci[lane], b = cj[lane];
        float dx = a.x - b.x, dy = a.y - b.y, dz = a.z - b.z, dw = a.w - b.w;
        float local = dx * dx + dy * dy + dz * dz + dw * dw;
        #pragma unroll
        for (int o = 32; o; o >>= 1) local += __shfl_xor(local, o, 64);
        wsum += sqrtf(fmaxf(local, 1e-12f));
        if (++j == CLUSTER) { ++i; j = i + 1; }
    }

    __shared__ float bsum[4];
    if (lane == 0) bsum[wave] = wsum;
    __syncthreads();
    if (threadIdx.x == 0)
        partials[blockIdx.x] = bsum[0] + bsum[1] + bsum[2] + bsum[3];
}

// ---------------- K4: final reduce of block partials -> -mean ---------------
__global__ __launch_bounds__(256) void k_final(const float* __restrict__ partials, int nb,
                                               float* __restrict__ out) {
    __shared__ float s[256];
    float acc = 0.f;
    for (int i = threadIdx.x; i < nb; i += 256) acc += partials[i];
    s[threadIdx.x] = acc;
    __syncthreads();
    for (int d = 128; d; d >>= 1) {
        if (threadIdx.x < d) s[threadIdx.x] += s[threadIdx.x + d];
        __syncthreads();
    }
    if (threadIdx.x == 0) out[0] = -s[0] / (float)NPAIR;
}

extern "C" void kernel_launch(void* const* d_in, const int* in_sizes, int n_in,
                              void* d_out, int out_size, void* d_ws, size_t ws_size,
                              hipStream_t stream) {
    const float* matrix = (const float*)d_in[0];
    const int* label = (const int*)d_in[1];
    float* out = (float*)d_out;

    // workspace layout (all fully overwritten each call; ~33 MB)
    float* partial   = (float*)d_ws;                                  // 512*64*256 floats = 32 MB
    float* centers   = partial + (size_t)CLUSTER * R * DIM;           // 512*256 floats
    float* ppart     = centers + (size_t)CLUSTER * DIM;               // 2044 floats
    int*   countpart = (int*)(ppart + 4096);                          // 64*512 ints

    k_gather<<<G * R, 256, 0, stream>>>(matrix, label, partial, countpart);
    k_center<<<CLUSTER, 256, 0, stream>>>(partial, countpart, centers);
    k_pairs<<<PAIR_BLOCKS, 256, 0, stream>>>(centers, ppart);
    k_final<<<1, 256, 0, stream>>>(ppart, PAIR_BLOCKS, out);
}